// Round 11
// baseline (725.209 us; speedup 1.0000x reference)
//
#include <hip/hip_runtime.h>
#include <hip/hip_bf16.h>
#include <math.h>

#define B_ 4
#define R_ 1024
#define G_ 8
#define E_ 192
#define H_ 6
#define D_ 32
#define L_ 4
#define F_ 384
#define M_ (B_*R_*G_)              // 32768 rows
static const size_t NBUF = (size_t)M_ * 192;      // 6291456 elems
static const size_t WPL  = 8 * (size_t)E_ * E_ + 2 * (size_t)E_ * F_;  // bf16/layer

typedef __attribute__((ext_vector_type(8))) short bf16x8;
typedef __attribute__((ext_vector_type(8))) unsigned short u16x8;
typedef __attribute__((ext_vector_type(4))) float f32x4;

__device__ __forceinline__ float gelu_exact(float x) {
    return 0.5f * x * (1.0f + erff(x * 0.7071067811865475f));
}
__device__ __forceinline__ unsigned short f2bf(float f) {
    __hip_bfloat16 h = __float2bfloat16(f);
    return *(unsigned short*)&h;
}
__device__ __forceinline__ float bf2f(unsigned short h) {
    union { unsigned u; float f; } v; v.u = ((unsigned)h) << 16; return v.f;
}
__device__ __forceinline__ bf16x8 mk8(unsigned long long lo, unsigned long long hi) {
    union { unsigned long long q[2]; bf16x8 v; } u;
    u.q[0] = lo; u.q[1] = hi; return u.v;
}

// ---- one-shot: transpose+convert all weights to Wt[N][K] bf16.
// Scale folds: Wq1 *= 1/sqrt(D); Wq2 *= log2(e)/sqrt(D)  (attn2 runs in exp2 domain).
__global__ __launch_bounds__(256)
void k_convw_all(const float* __restrict__ Wq1, const float* __restrict__ Wk1,
                 const float* __restrict__ Wv1, const float* __restrict__ Wo1,
                 const float* __restrict__ Wq2, const float* __restrict__ Wk2,
                 const float* __restrict__ Wv2, const float* __restrict__ Wo2,
                 const float* __restrict__ W1,  const float* __restrict__ W2,
                 unsigned short* __restrict__ Wt)
{
    const int t = blockIdx.x;
    const int layer = t / 432;
    const int r = t % 432;
    const float* src; unsigned short* dst; int K, N; float scale = 1.f; int tile;
    if (r < 288) {
        const int w = r / 36; tile = r % 36; K = E_; N = E_;
        const float* tab[8] = {Wq1, Wk1, Wv1, Wo1, Wq2, Wk2, Wv2, Wo2};
        src = tab[w] + (size_t)layer * E_ * E_;
        dst = Wt + (size_t)layer * WPL + (size_t)w * E_ * E_;
        if (w == 0) scale = 0.17677669529663687f;                       // 1/sqrt(32)
        if (w == 4) scale = 0.17677669529663687f * 1.4426950408889634f; // log2e/sqrt(32)
    } else if (r < 360) {
        tile = r - 288; K = E_; N = F_;
        src = W1 + (size_t)layer * E_ * F_;
        dst = Wt + (size_t)layer * WPL + 8 * (size_t)E_ * E_;
    } else {
        tile = r - 360; K = F_; N = E_;
        src = W2 + (size_t)layer * E_ * F_;
        dst = Wt + (size_t)layer * WPL + 8 * (size_t)E_ * E_ + (size_t)E_ * F_;
    }
    const int ntx = N / 32;
    const int kb = (tile / ntx) * 32, nb = (tile % ntx) * 32;
    __shared__ float tl[32][33];
    const int tx = threadIdx.x & 31, ty = threadIdx.x >> 5;
    for (int i2 = 0; i2 < 32; i2 += 8)
        tl[ty + i2][tx] = src[(size_t)(kb + ty + i2) * N + nb + tx];
    __syncthreads();
    for (int i2 = 0; i2 < 32; i2 += 8)
        dst[(size_t)(nb + ty + i2) * K + kb + tx] = f2bf(tl[tx][ty + i2] * scale);
}

// ---- MFMA GEMM, tile 64 x 192, BK=32, 4 waves, reg-prefetch pipeline (R8 form).
// EPI: 0 = store bf16 at [m][n0+n], ldc; 1 = gelu -> bf16, ldc.
template<bool ABF16, int EPI>
__global__ __launch_bounds__(256)
void k_gemm_mfma(const void* __restrict__ Ap, const unsigned short* __restrict__ Wt,
                 void* __restrict__ Cp, int ldc, int K)
{
    __shared__ unsigned short As[64][40];
    __shared__ unsigned short Bs[192][40];
    const int m0 = blockIdx.x * 64;
    const int n0 = blockIdx.y * 192;
    const int tid = threadIdx.x;
    const int w = tid >> 6, lane = tid & 63, l15 = lane & 15, g = lane >> 4;
    const int arow = tid >> 2, akoff = (tid & 3) << 3;
    f32x4 acc[4][3];
#pragma unroll
    for (int mt = 0; mt < 4; ++mt)
#pragma unroll
        for (int nt = 0; nt < 3; ++nt)
#pragma unroll
            for (int r2 = 0; r2 < 4; ++r2) acc[mt][nt][r2] = 0.f;
    const int nK = K >> 5;

    float4 ax, ay; u16x8 av; u16x8 bv0, bv1, bv2;
    auto gload = [&](int k0) {
        if (ABF16) {
            av = *(const u16x8*)((const unsigned short*)Ap + (size_t)(m0 + arow) * K + k0 + akoff);
        } else {
            const float* ap = (const float*)Ap + (size_t)(m0 + arow) * K + k0 + akoff;
            ax = *(const float4*)ap; ay = *(const float4*)(ap + 4);
        }
        bv0 = *(const u16x8*)(Wt + (size_t)(n0 + arow      ) * K + k0 + akoff);
        bv1 = *(const u16x8*)(Wt + (size_t)(n0 + arow +  64) * K + k0 + akoff);
        bv2 = *(const u16x8*)(Wt + (size_t)(n0 + arow + 128) * K + k0 + akoff);
    };
    auto swrite = [&]() {
        u16x8 aw;
        if (ABF16) aw = av;
        else {
            aw[0] = f2bf(ax.x); aw[1] = f2bf(ax.y); aw[2] = f2bf(ax.z); aw[3] = f2bf(ax.w);
            aw[4] = f2bf(ay.x); aw[5] = f2bf(ay.y); aw[6] = f2bf(ay.z); aw[7] = f2bf(ay.w);
        }
        *(u16x8*)&As[arow][akoff] = aw;
        *(u16x8*)&Bs[arow][akoff] = bv0;
        *(u16x8*)&Bs[arow + 64][akoff] = bv1;
        *(u16x8*)&Bs[arow + 128][akoff] = bv2;
    };

    gload(0);
    for (int kc = 0; kc < nK; ++kc) {
        __syncthreads();
        swrite();
        __syncthreads();
        if (kc + 1 < nK) gload((kc + 1) << 5);
        bf16x8 af[4], bfr[3];
#pragma unroll
        for (int mt = 0; mt < 4; ++mt) af[mt] = *(const bf16x8*)&As[mt * 16 + l15][g * 8];
#pragma unroll
        for (int nt = 0; nt < 3; ++nt) bfr[nt] = *(const bf16x8*)&Bs[w * 48 + nt * 16 + l15][g * 8];
#pragma unroll
        for (int mt = 0; mt < 4; ++mt)
#pragma unroll
            for (int nt = 0; nt < 3; ++nt)
                acc[mt][nt] = __builtin_amdgcn_mfma_f32_16x16x32_bf16(af[mt], bfr[nt], acc[mt][nt], 0, 0, 0);
    }

#pragma unroll
    for (int mt = 0; mt < 4; ++mt)
#pragma unroll
        for (int r2 = 0; r2 < 4; ++r2) {
            const int m = m0 + mt * 16 + g * 4 + r2;
#pragma unroll
            for (int nt = 0; nt < 3; ++nt) {
                const int n = w * 48 + nt * 16 + l15;
                float v = acc[mt][nt][r2];
                if (EPI == 1) v = gelu_exact(v);
                ((unsigned short*)Cp)[(size_t)m * ldc + n0 + n] = f2bf(v);
            }
        }
}

// ---- MFMA GEMM + residual + row-RMSNorm, tile 32 x 192, 4 waves, grid M/32 (R8 form).
// EPI: 2 = ->bf16, transpose X->XR; 3 = ->bf16, XR->X; 4 = ->f32; 5 = ->bf16.
template<bool RESBF16, int EPI>
__global__ __launch_bounds__(256)
void k_gemm_rms32(const unsigned short* __restrict__ Ap, const unsigned short* __restrict__ Wt,
                  const void* __restrict__ Resp, const float* __restrict__ gvec,
                  void* __restrict__ Cp, int K)
{
    __shared__ unsigned short As[32][40];
    __shared__ unsigned short Bs[192][40];
    __shared__ float ss_red[4][16];
    const int m0 = blockIdx.x * 32;
    const int tid = threadIdx.x;
    const int w = tid >> 6, lane = tid & 63, l15 = lane & 15, g = lane >> 4;
    const int mt = w & 1, nh = w >> 1;
    const int arow = tid >> 2, akoff = (tid & 3) << 3;
    f32x4 acc[6];
#pragma unroll
    for (int nt = 0; nt < 6; ++nt)
#pragma unroll
        for (int r2 = 0; r2 < 4; ++r2) acc[nt][r2] = 0.f;
    const int nK = K >> 5;

    u16x8 av, bv0, bv1, bv2;
    auto gload = [&](int k0) {
        if (tid < 128)
            av = *(const u16x8*)(Ap + (size_t)(m0 + arow) * K + k0 + akoff);
        bv0 = *(const u16x8*)(Wt + (size_t)(arow      ) * K + k0 + akoff);
        bv1 = *(const u16x8*)(Wt + (size_t)(arow +  64) * K + k0 + akoff);
        bv2 = *(const u16x8*)(Wt + (size_t)(arow + 128) * K + k0 + akoff);
    };
    auto swrite = [&]() {
        if (tid < 128) *(u16x8*)&As[arow][akoff] = av;
        *(u16x8*)&Bs[arow][akoff] = bv0;
        *(u16x8*)&Bs[arow + 64][akoff] = bv1;
        *(u16x8*)&Bs[arow + 128][akoff] = bv2;
    };

    gload(0);
    for (int kc = 0; kc < nK; ++kc) {
        __syncthreads();
        swrite();
        __syncthreads();
        if (kc + 1 < nK) gload((kc + 1) << 5);
        bf16x8 af = *(const bf16x8*)&As[mt * 16 + l15][g * 8];
        bf16x8 bfr[6];
#pragma unroll
        for (int nt = 0; nt < 6; ++nt) bfr[nt] = *(const bf16x8*)&Bs[nh * 96 + nt * 16 + l15][g * 8];
#pragma unroll
        for (int nt = 0; nt < 6; ++nt)
            acc[nt] = __builtin_amdgcn_mfma_f32_16x16x32_bf16(af, bfr[nt], acc[nt], 0, 0, 0);
    }

    float ssp[4] = {0.f, 0.f, 0.f, 0.f};
#pragma unroll
    for (int r2 = 0; r2 < 4; ++r2) {
        const int m = m0 + mt * 16 + g * 4 + r2;
#pragma unroll
        for (int nt = 0; nt < 6; ++nt) {
            const int n = nh * 96 + nt * 16 + l15;
            float rres = RESBF16 ? bf2f(((const unsigned short*)Resp)[(size_t)m * E_ + n])
                                 : ((const float*)Resp)[(size_t)m * E_ + n];
            float v = acc[nt][r2] + rres;
            acc[nt][r2] = v;
            ssp[r2] += v * v;
        }
    }
#pragma unroll
    for (int off = 1; off < 16; off <<= 1)
#pragma unroll
        for (int r2 = 0; r2 < 4; ++r2)
            ssp[r2] += __shfl_xor(ssp[r2], off);
    if (l15 == 0) {
#pragma unroll
        for (int r2 = 0; r2 < 4; ++r2)
            ss_red[w][g * 4 + r2] = ssp[r2];
    }
    __syncthreads();
#pragma unroll
    for (int r2 = 0; r2 < 4; ++r2) {
        const int lr = g * 4 + r2;
        const float ss = ss_red[mt][lr] + ss_red[2 + mt][lr];
        const float inv = rsqrtf(ss * (1.0f / 192.0f) + 1.1920929e-07f);
        const int m = m0 + mt * 16 + lr;
        size_t orow;
        if (EPI == 2) {        // X -> XR
            const int b = m >> 13, rr = (m >> 3) & 1023, gg = m & 7;
            orow = (((size_t)b * G_ + gg) << 10) + rr;
        } else if (EPI == 3) { // XR -> X
            const int b = m >> 13, gg = (m >> 10) & 7, rr = m & 1023;
            orow = ((((size_t)b << 10) + rr) << 3) + gg;
        } else {
            orow = m;
        }
#pragma unroll
        for (int nt = 0; nt < 6; ++nt) {
            const int n = nh * 96 + nt * 16 + l15;
            const float v = acc[nt][r2] * inv * gvec[n];
            if (EPI == 4) ((float*)Cp)[orow * E_ + n] = v;
            else          ((unsigned short*)Cp)[orow * E_ + n] = f2bf(v);
        }
    }
}

// ---- Feature-group attention. QKV fused buffer [M][576]: Q=0, K=+192, V=+384.
__global__ __launch_bounds__(256)
void k_attn1(const unsigned short* __restrict__ QKV, unsigned short* __restrict__ T)
{
    const int wave = blockIdx.x * 4 + (threadIdx.x >> 6);
    const int lane = threadIdx.x & 63;
    const int seq = wave / H_;
    const int h = wave % H_;
    const int i = lane >> 3, j = lane & 7;
    const unsigned short* qp = QKV + ((size_t)(seq * G_ + i)) * 576 + h * D_;
    const unsigned short* kp = QKV + ((size_t)(seq * G_ + j)) * 576 + 192 + h * D_;
    float s = 0.f;
#pragma unroll
    for (int d8 = 0; d8 < 4; ++d8) {
        u16x8 qv = *(const u16x8*)(qp + d8 * 8);
        u16x8 kv = *(const u16x8*)(kp + d8 * 8);
#pragma unroll
        for (int e = 0; e < 8; ++e) s += bf2f(qv[e]) * bf2f(kv[e]);
    }
    float mx = s;
#pragma unroll
    for (int off = 1; off < 8; off <<= 1) mx = fmaxf(mx, __shfl_xor(mx, off));
    float p = __expf(s - mx);
    float sum = p;
#pragma unroll
    for (int off = 1; off < 8; off <<= 1) sum += __shfl_xor(sum, off);
    p /= sum;
    const int base = lane & ~7;
    float o0 = 0.f, o1 = 0.f, o2 = 0.f, o3 = 0.f;
#pragma unroll
    for (int jj = 0; jj < 8; ++jj) {
        float pj = __shfl(p, base + jj);
        ushort4 vv = *(const ushort4*)(QKV + ((size_t)(seq * G_ + jj)) * 576 + 384 + h * D_ + j * 4);
        o0 += pj * bf2f(vv.x); o1 += pj * bf2f(vv.y);
        o2 += pj * bf2f(vv.z); o3 += pj * bf2f(vv.w);
    }
    ushort4 ov; ov.x = f2bf(o0); ov.y = f2bf(o1); ov.z = f2bf(o2); ov.w = f2bf(o3);
    *(ushort4*)(T + ((size_t)(seq * G_ + i)) * E_ + h * D_ + j * 4) = ov;
}

// ---- Row attention, MFMA flash, exp2 domain. 128-q per block (4 waves x 2
// sub-tiles of 16 q): K fragments (4 ds_read_b128) and V fragments (8 tr-reads)
// loaded ONCE per wave per chunk and reused by both sub-tiles — per-q LDS and
// barrier cost halved vs 64-q. Register-resident P, ones-row denominator,
// defer-max. Grid 1536 = 6 blocks/CU.
__global__ __launch_bounds__(256)
void k_attn2(const unsigned short* __restrict__ QKV, unsigned short* __restrict__ T,
             const int* __restrict__ sep_ptr)
{
    __shared__ __align__(16) unsigned short K_lds[64][40];
    __shared__ __align__(16) unsigned short V_lds[2048];   // [dg(2)][kblk(16)][4][16]

    const int sep = *sep_ptr;
    const int bid = blockIdx.x;
    const int sh = ((bid >> 6) << 3) | (bid & 7);   // same (s,h) => same XCD
    const int qtile = (bid >> 3) & 7;
    const int s = sh / H_, h = sh % H_;
    const int q0 = qtile * 128;

    const int tid = threadIdx.x;
    const int w = tid >> 6;
    const int lane = tid & 63;
    const int l15 = lane & 15;
    const int g = lane >> 4;

    const int qrow0 = q0 + w * 32 + l15;            // sub0 row; sub1 = +16
    u16x8 qf0 = *(const u16x8*)(QKV + ((size_t)s * R_ + qrow0) * 576 + h * D_ + g * 8);
    u16x8 qf1 = *(const u16x8*)(QKV + ((size_t)s * R_ + qrow0 + 16) * 576 + h * D_ + g * 8);

    u16x8 onesu;
#pragma unroll
    for (int e = 0; e < 8; ++e) onesu[e] = 0x3F80;  // bf16 1.0
    const bf16x8 onesf = (bf16x8)onesu;

    const bool lo = (q0 < sep);
    const bool hi = (q0 + 128 > sep);
    const int npass = (lo && hi) ? 2 : 1;
    const int nChunk = (sep + 63) >> 6;

    const int skey = tid >> 2;
    const int sg   = tid & 3;
    const int vst = ((sg >> 1) * 16 + (skey >> 2)) * 64 + (skey & 3) * 16 + (sg & 1) * 8;
    const unsigned vaddr = (unsigned)(size_t)&V_lds[0] + (unsigned)(g * 128 + l15 * 2);

    for (int pass = 0; pass < npass; ++pass) {
        const int hk = (pass == 0) ? (lo ? h : 0) : 0;
        const unsigned short* Kb = QKV + (size_t)s * R_ * 576 + 192 + hk * D_;
        const unsigned short* Vb = QKV + (size_t)s * R_ * 576 + 384 + hk * D_;

        float m0r = -1e30f, m1r = -1e30f;
        f32x4 o0a = {0.f,0.f,0.f,0.f}, o0b = {0.f,0.f,0.f,0.f}, o0c = {0.f,0.f,0.f,0.f};
        f32x4 o1a = {0.f,0.f,0.f,0.f}, o1b = {0.f,0.f,0.f,0.f}, o1c = {0.f,0.f,0.f,0.f};

        // prologue: prefetch chunk 0 into regs
        u16x8 kv_k = *(const u16x8*)(Kb + (size_t)skey * 576 + sg * 8);
        u16x8 kv_v = *(const u16x8*)(Vb + (size_t)skey * 576 + sg * 8);

        for (int kc = 0; kc < nChunk; ++kc) {
            const int kbase = kc * 64;
            const bool full = (kbase + 64 <= sep);
            __syncthreads();
            *(u16x8*)&K_lds[skey][sg * 8] = kv_k;
            *(u16x8*)&V_lds[vst] = kv_v;
            __syncthreads();
            if (kc + 1 < nChunk) {
                kv_k = *(const u16x8*)(Kb + (size_t)(kbase + 64 + skey) * 576 + sg * 8);
                kv_v = *(const u16x8*)(Vb + (size_t)(kbase + 64 + skey) * 576 + sg * 8);
            }

            // K fragments, shared by both sub-tiles
            bf16x8 kfr0 = *(const bf16x8*)&K_lds[l15][g * 8];
            bf16x8 kfr1 = *(const bf16x8*)&K_lds[16 + l15][g * 8];
            bf16x8 kfr2 = *(const bf16x8*)&K_lds[32 + l15][g * 8];
            bf16x8 kfr3 = *(const bf16x8*)&K_lds[48 + l15][g * 8];
            // V^T fragments via hardware transpose reads, shared by both sub-tiles
            unsigned long long t0, t1, t2, t3, t4, t5, t6, t7;
            asm volatile(
                "ds_read_b64_tr_b16 %0, %8 offset:0\n\t"
                "ds_read_b64_tr_b16 %1, %8 offset:512\n\t"
                "ds_read_b64_tr_b16 %2, %8 offset:1024\n\t"
                "ds_read_b64_tr_b16 %3, %8 offset:1536\n\t"
                "ds_read_b64_tr_b16 %4, %8 offset:2048\n\t"
                "ds_read_b64_tr_b16 %5, %8 offset:2560\n\t"
                "ds_read_b64_tr_b16 %6, %8 offset:3072\n\t"
                "ds_read_b64_tr_b16 %7, %8 offset:3584\n\t"
                "s_waitcnt lgkmcnt(0)"
                : "=&v"(t0), "=&v"(t1), "=&v"(t2), "=&v"(t3),
                  "=&v"(t4), "=&v"(t5), "=&v"(t6), "=&v"(t7)
                : "v"(vaddr)
                : "memory");
            __builtin_amdgcn_sched_barrier(0);

            auto process = [&](const u16x8& qf, float& mrun,
                               f32x4& oa, f32x4& ob, f32x4& oc) {
                f32x4 sc[4];
                const f32x4 zf = {0.f, 0.f, 0.f, 0.f};
                __builtin_amdgcn_s_setprio(1);
                sc[0] = __builtin_amdgcn_mfma_f32_16x16x32_bf16(kfr0, (bf16x8)qf, zf, 0, 0, 0);
                sc[1] = __builtin_amdgcn_mfma_f32_16x16x32_bf16(kfr1, (bf16x8)qf, zf, 0, 0, 0);
                sc[2] = __builtin_amdgcn_mfma_f32_16x16x32_bf16(kfr2, (bf16x8)qf, zf, 0, 0, 0);
                sc[3] = __builtin_amdgcn_mfma_f32_16x16x32_bf16(kfr3, (bf16x8)qf, zf, 0, 0, 0);
                __builtin_amdgcn_s_setprio(0);
                if (!full) {
#pragma unroll
                    for (int t = 0; t < 4; ++t)
#pragma unroll
                        for (int r = 0; r < 4; ++r)
                            if (kbase + t * 16 + g * 4 + r >= sep) sc[t][r] = -1e30f;
                }
                float mx = fmaxf(fmaxf(sc[0][0], sc[0][1]), sc[0][2]);
                mx = fmaxf(fmaxf(sc[0][3], sc[1][0]), mx);
                mx = fmaxf(fmaxf(sc[1][1], sc[1][2]), mx);
                mx = fmaxf(fmaxf(sc[1][3], sc[2][0]), mx);
                mx = fmaxf(fmaxf(sc[2][1], sc[2][2]), mx);
                mx = fmaxf(fmaxf(sc[2][3], sc[3][0]), mx);
                mx = fmaxf(fmaxf(sc[3][1], sc[3][2]), mx);
                mx = fmaxf(mx, sc[3][3]);
                if (!__all((int)(mx <= mrun + 11.0f))) {
                    mx = fmaxf(mx, __shfl_xor(mx, 16));
                    mx = fmaxf(mx, __shfl_xor(mx, 32));
                    const float mnew = fmaxf(mrun, mx);
                    const float scl = exp2f(mrun - mnew);
#pragma unroll
                    for (int r = 0; r < 4; ++r) { oa[r] *= scl; ob[r] *= scl; oc[r] *= scl; }
                    mrun = mnew;
                }
                bf16x8 pb0, pb1;
                {
                    u16x8 p0, p1;
#pragma unroll
                    for (int r = 0; r < 4; ++r) {
                        p0[r]     = f2bf(exp2f(sc[0][r] - mrun));
                        p0[4 + r] = f2bf(exp2f(sc[1][r] - mrun));
                        p1[r]     = f2bf(exp2f(sc[2][r] - mrun));
                        p1[4 + r] = f2bf(exp2f(sc[3][r] - mrun));
                    }
                    pb0 = (bf16x8)p0; pb1 = (bf16x8)p1;
                }
                __builtin_amdgcn_s_setprio(1);
                oa = __builtin_amdgcn_mfma_f32_16x16x32_bf16(mk8(t0, t1), pb0, oa, 0, 0, 0);
                ob = __builtin_amdgcn_mfma_f32_16x16x32_bf16(mk8(t4, t5), pb0, ob, 0, 0, 0);
                oc = __builtin_amdgcn_mfma_f32_16x16x32_bf16(onesf,       pb0, oc, 0, 0, 0);
                oa = __builtin_amdgcn_mfma_f32_16x16x32_bf16(mk8(t2, t3), pb1, oa, 0, 0, 0);
                ob = __builtin_amdgcn_mfma_f32_16x16x32_bf16(mk8(t6, t7), pb1, ob, 0, 0, 0);
                oc = __builtin_amdgcn_mfma_f32_16x16x32_bf16(onesf,       pb1, oc, 0, 0, 0);
                __builtin_amdgcn_s_setprio(0);
            };
            process(qf0, m0r, o0a, o0b, o0c);
            process(qf1, m1r, o1a, o1b, o1c);
        }

        auto epi = [&](int qrow, const f32x4& oa, const f32x4& ob, const f32x4& oc) {
            const bool valid = (npass == 1) || (pass == 0 ? (qrow < sep) : (qrow >= sep));
            if (valid) {
                const float inv = 1.f / oc[0];   // sum_k P[q][k]
                unsigned short* tp = T + ((size_t)s * R_ + qrow) * E_ + h * D_;
                ushort4 v0, v1;
                v0.x = f2bf(oa[0] * inv); v0.y = f2bf(oa[1] * inv);
                v0.z = f2bf(oa[2] * inv); v0.w = f2bf(oa[3] * inv);
                v1.x = f2bf(ob[0] * inv); v1.y = f2bf(ob[1] * inv);
                v1.z = f2bf(ob[2] * inv); v1.w = f2bf(ob[3] * inv);
                *(ushort4*)(tp + g * 4)      = v0;
                *(ushort4*)(tp + 16 + g * 4) = v1;
            }
        };
        epi(qrow0,      o0a, o0b, o0c);
        epi(qrow0 + 16, o1a, o1b, o1c);
    }
}

extern "C" void kernel_launch(void* const* d_in, const int* in_sizes, int n_in,
                              void* d_out, int out_size, void* d_ws, size_t ws_size,
                              hipStream_t stream) {
    const float* hidden = (const float*)d_in[0];
    const float* Wq1 = (const float*)d_in[1];
    const float* Wk1 = (const float*)d_in[2];
    const float* Wv1 = (const float*)d_in[3];
    const float* Wo1 = (const float*)d_in[4];
    const float* Wq2 = (const float*)d_in[5];
    const float* Wk2 = (const float*)d_in[6];
    const float* Wv2 = (const float*)d_in[7];
    const float* Wo2 = (const float*)d_in[8];
    const float* W1  = (const float*)d_in[9];
    const float* W2  = (const float*)d_in[10];
    const float* g1  = (const float*)d_in[11];
    const float* g2  = (const float*)d_in[12];
    const float* g3  = (const float*)d_in[13];
    const int*   sep = (const int*)d_in[14];

    float* Xout = (float*)d_out;                    // final f32 X-layout output
    unsigned short* ws = (unsigned short*)d_ws;
    unsigned short* QKVb = ws;                      // [M][576] bf16 (aliases H1 [M][384])
    unsigned short* Tb   = QKVb + (size_t)M_ * 576;
    unsigned short* Ynb  = Tb + NBUF;               // rms-g1 output, XR layout
    unsigned short* Xcb  = Ynb + NBUF;              // rms-g2 output, X layout
    unsigned short* Xb   = Xcb + NBUF;              // inter-layer residual (layers 0-2)
    unsigned short* Wt   = Xb + NBUF;
    unsigned short* H1b  = QKVb;

    const dim3 blk(256);
    const dim3 gQKV(M_ / 64, 3);
    const dim3 gW1(M_ / 64, 2);
    const dim3 g32(M_ / 32);                        // rms-GEMM: 1024 blocks, 4/CU
    const dim3 gA1((4096 * H_) / 4);
    const dim3 gA2(32 * H_ * 8);                    // (s,h) x 8 q-tiles of 128 rows

    k_convw_all<<<dim3(432 * L_), blk, 0, stream>>>(Wq1, Wk1, Wv1, Wo1, Wq2, Wk2, Wv2, Wo2, W1, W2, Wt);

    for (int i = 0; i < L_; ++i) {
        unsigned short* wl = Wt + (size_t)i * WPL;
        const unsigned short* wqkv1 = wl;
        const unsigned short* wo1   = wl + 3 * (size_t)E_ * E_;
        const unsigned short* wqkv2 = wl + 4 * (size_t)E_ * E_;
        const unsigned short* wo2   = wl + 7 * (size_t)E_ * E_;
        const unsigned short* w1    = wl + 8 * (size_t)E_ * E_;
        const unsigned short* w2    = wl + 8 * (size_t)E_ * E_ + (size_t)E_ * F_;
        const float* g1i = g1 + (size_t)i * E_;
        const float* g2i = g2 + (size_t)i * E_;
        const float* g3i = g3 + (size_t)i * E_;

        // --- feature-group attention block ---
        if (i == 0)
            k_gemm_mfma<false, 0><<<gQKV, blk, 0, stream>>>(hidden, wqkv1, QKVb, 576, E_);
        else
            k_gemm_mfma<true, 0><<<gQKV, blk, 0, stream>>>(Xb, wqkv1, QKVb, 576, E_);
        k_attn1<<<gA1, blk, 0, stream>>>(QKVb, Tb);
        if (i == 0)
            k_gemm_rms32<false, 2><<<g32, blk, 0, stream>>>(Tb, wo1, hidden, g1i, Ynb, E_);
        else
            k_gemm_rms32<true, 2><<<g32, blk, 0, stream>>>(Tb, wo1, Xb, g1i, Ynb, E_);
        // --- row attention block ---
        k_gemm_mfma<true, 0><<<gQKV, blk, 0, stream>>>(Ynb, wqkv2, QKVb, 576, E_);
        k_attn2<<<gA2, blk, 0, stream>>>(QKVb, Tb, sep);
        k_gemm_rms32<true, 3><<<g32, blk, 0, stream>>>(Tb, wo2, Ynb, g2i, Xcb, E_);
        // --- MLP block ---
        k_gemm_mfma<true, 1><<<gW1, blk, 0, stream>>>(Xcb, w1, H1b, F_, E_);
        if (i == L_ - 1)
            k_gemm_rms32<true, 4><<<g32, blk, 0, stream>>>(H1b, w2, Xcb, g3i, Xout, F_);
        else
            k_gemm_rms32<true, 5><<<g32, blk, 0, stream>>>(H1b, w2, Xcb, g3i, Xb, F_);
    }
}

// Round 12
// 641.567 us; speedup vs baseline: 1.1304x; 1.1304x over previous
//
#include <hip/hip_runtime.h>
#include <hip/hip_bf16.h>
#include <math.h>

#define B_ 4
#define R_ 1024
#define G_ 8
#define E_ 192
#define H_ 6
#define D_ 32
#define L_ 4
#define F_ 384
#define M_ (B_*R_*G_)              // 32768 rows
static const size_t NBUF = (size_t)M_ * E_;       // 6291456 elems
static const size_t WPL  = 8 * (size_t)E_ * E_ + 2 * (size_t)E_ * F_;  // bf16/layer

typedef __attribute__((ext_vector_type(8))) short bf16x8;
typedef __attribute__((ext_vector_type(8))) unsigned short u16x8;
typedef __attribute__((ext_vector_type(4))) float f32x4;

__device__ __forceinline__ float gelu_exact(float x) {
    return 0.5f * x * (1.0f + erff(x * 0.7071067811865475f));
}
__device__ __forceinline__ unsigned short f2bf(float f) {
    __hip_bfloat16 h = __float2bfloat16(f);
    return *(unsigned short*)&h;
}
__device__ __forceinline__ float bf2f(unsigned short h) {
    union { unsigned u; float f; } v; v.u = ((unsigned)h) << 16; return v.f;
}
__device__ __forceinline__ bf16x8 mk8(unsigned long long lo, unsigned long long hi) {
    union { unsigned long long q[2]; bf16x8 v; } u;
    u.q[0] = lo; u.q[1] = hi; return u.v;
}

// ---- one-shot: transpose+convert all weights to Wt[N][K] bf16.
// Scale folds: Wq1 *= 1/sqrt(D); Wq2 *= log2(e)/sqrt(D)  (attn2 runs in exp2 domain).
__global__ __launch_bounds__(256)
void k_convw_all(const float* __restrict__ Wq1, const float* __restrict__ Wk1,
                 const float* __restrict__ Wv1, const float* __restrict__ Wo1,
                 const float* __restrict__ Wq2, const float* __restrict__ Wk2,
                 const float* __restrict__ Wv2, const float* __restrict__ Wo2,
                 const float* __restrict__ W1,  const float* __restrict__ W2,
                 unsigned short* __restrict__ Wt)
{
    const int t = blockIdx.x;
    const int layer = t / 432;
    const int r = t % 432;
    const float* src; unsigned short* dst; int K, N; float scale = 1.f; int tile;
    if (r < 288) {
        const int w = r / 36; tile = r % 36; K = E_; N = E_;
        const float* tab[8] = {Wq1, Wk1, Wv1, Wo1, Wq2, Wk2, Wv2, Wo2};
        src = tab[w] + (size_t)layer * E_ * E_;
        dst = Wt + (size_t)layer * WPL + (size_t)w * E_ * E_;
        if (w == 0) scale = 0.17677669529663687f;                       // 1/sqrt(32)
        if (w == 4) scale = 0.17677669529663687f * 1.4426950408889634f; // log2e/sqrt(32)
    } else if (r < 360) {
        tile = r - 288; K = E_; N = F_;
        src = W1 + (size_t)layer * E_ * F_;
        dst = Wt + (size_t)layer * WPL + 8 * (size_t)E_ * E_;
    } else {
        tile = r - 360; K = F_; N = E_;
        src = W2 + (size_t)layer * E_ * F_;
        dst = Wt + (size_t)layer * WPL + 8 * (size_t)E_ * E_ + (size_t)E_ * F_;
    }
    const int ntx = N / 32;
    const int kb = (tile / ntx) * 32, nb = (tile % ntx) * 32;
    __shared__ float tl[32][33];
    const int tx = threadIdx.x & 31, ty = threadIdx.x >> 5;
    for (int i2 = 0; i2 < 32; i2 += 8)
        tl[ty + i2][tx] = src[(size_t)(kb + ty + i2) * N + nb + tx];
    __syncthreads();
    for (int i2 = 0; i2 < 32; i2 += 8)
        dst[(size_t)(nb + ty + i2) * K + kb + tx] = f2bf(tl[tx][ty + i2] * scale);
}

// ---- MFMA GEMM, tile 64 x 192, BK=32, 4 waves, reg-prefetch pipeline (R8 form).
// EPI: 0 = store bf16 at [m][n0+n], ldc; 1 = gelu -> bf16, ldc.
template<bool ABF16, int EPI>
__global__ __launch_bounds__(256)
void k_gemm_mfma(const void* __restrict__ Ap, const unsigned short* __restrict__ Wt,
                 void* __restrict__ Cp, int ldc, int K)
{
    __shared__ unsigned short As[64][40];
    __shared__ unsigned short Bs[192][40];
    const int m0 = blockIdx.x * 64;
    const int n0 = blockIdx.y * 192;
    const int tid = threadIdx.x;
    const int w = tid >> 6, lane = tid & 63, l15 = lane & 15, g = lane >> 4;
    const int arow = tid >> 2, akoff = (tid & 3) << 3;
    f32x4 acc[4][3];
#pragma unroll
    for (int mt = 0; mt < 4; ++mt)
#pragma unroll
        for (int nt = 0; nt < 3; ++nt)
#pragma unroll
            for (int r2 = 0; r2 < 4; ++r2) acc[mt][nt][r2] = 0.f;
    const int nK = K >> 5;

    float4 ax, ay; u16x8 av; u16x8 bv0, bv1, bv2;
    auto gload = [&](int k0) {
        if (ABF16) {
            av = *(const u16x8*)((const unsigned short*)Ap + (size_t)(m0 + arow) * K + k0 + akoff);
        } else {
            const float* ap = (const float*)Ap + (size_t)(m0 + arow) * K + k0 + akoff;
            ax = *(const float4*)ap; ay = *(const float4*)(ap + 4);
        }
        bv0 = *(const u16x8*)(Wt + (size_t)(n0 + arow      ) * K + k0 + akoff);
        bv1 = *(const u16x8*)(Wt + (size_t)(n0 + arow +  64) * K + k0 + akoff);
        bv2 = *(const u16x8*)(Wt + (size_t)(n0 + arow + 128) * K + k0 + akoff);
    };
    auto swrite = [&]() {
        u16x8 aw;
        if (ABF16) aw = av;
        else {
            aw[0] = f2bf(ax.x); aw[1] = f2bf(ax.y); aw[2] = f2bf(ax.z); aw[3] = f2bf(ax.w);
            aw[4] = f2bf(ay.x); aw[5] = f2bf(ay.y); aw[6] = f2bf(ay.z); aw[7] = f2bf(ay.w);
        }
        *(u16x8*)&As[arow][akoff] = aw;
        *(u16x8*)&Bs[arow][akoff] = bv0;
        *(u16x8*)&Bs[arow + 64][akoff] = bv1;
        *(u16x8*)&Bs[arow + 128][akoff] = bv2;
    };

    gload(0);
    for (int kc = 0; kc < nK; ++kc) {
        __syncthreads();
        swrite();
        __syncthreads();
        if (kc + 1 < nK) gload((kc + 1) << 5);
        bf16x8 af[4], bfr[3];
#pragma unroll
        for (int mt = 0; mt < 4; ++mt) af[mt] = *(const bf16x8*)&As[mt * 16 + l15][g * 8];
#pragma unroll
        for (int nt = 0; nt < 3; ++nt) bfr[nt] = *(const bf16x8*)&Bs[w * 48 + nt * 16 + l15][g * 8];
#pragma unroll
        for (int mt = 0; mt < 4; ++mt)
#pragma unroll
            for (int nt = 0; nt < 3; ++nt)
                acc[mt][nt] = __builtin_amdgcn_mfma_f32_16x16x32_bf16(af[mt], bfr[nt], acc[mt][nt], 0, 0, 0);
    }

#pragma unroll
    for (int mt = 0; mt < 4; ++mt)
#pragma unroll
        for (int r2 = 0; r2 < 4; ++r2) {
            const int m = m0 + mt * 16 + g * 4 + r2;
#pragma unroll
            for (int nt = 0; nt < 3; ++nt) {
                const int n = w * 48 + nt * 16 + l15;
                float v = acc[mt][nt][r2];
                if (EPI == 1) v = gelu_exact(v);
                ((unsigned short*)Cp)[(size_t)m * ldc + n0 + n] = f2bf(v);
            }
        }
}

// ---- MFMA GEMM + residual + row-RMSNorm, tile 32 x 192, 4 waves, grid M/32 (R8 form).
// EPI: 2 = ->bf16, transpose X->XR; 3 = ->bf16, XR->X; 4 = ->f32; 5 = ->bf16.
template<bool RESBF16, int EPI>
__global__ __launch_bounds__(256)
void k_gemm_rms32(const unsigned short* __restrict__ Ap, const unsigned short* __restrict__ Wt,
                  const void* __restrict__ Resp, const float* __restrict__ gvec,
                  void* __restrict__ Cp, int K)
{
    __shared__ unsigned short As[32][40];
    __shared__ unsigned short Bs[192][40];
    __shared__ float ss_red[4][16];
    const int m0 = blockIdx.x * 32;
    const int tid = threadIdx.x;
    const int w = tid >> 6, lane = tid & 63, l15 = lane & 15, g = lane >> 4;
    const int mt = w & 1, nh = w >> 1;
    const int arow = tid >> 2, akoff = (tid & 3) << 3;
    f32x4 acc[6];
#pragma unroll
    for (int nt = 0; nt < 6; ++nt)
#pragma unroll
        for (int r2 = 0; r2 < 4; ++r2) acc[nt][r2] = 0.f;
    const int nK = K >> 5;

    u16x8 av, bv0, bv1, bv2;
    auto gload = [&](int k0) {
        if (tid < 128)
            av = *(const u16x8*)(Ap + (size_t)(m0 + arow) * K + k0 + akoff);
        bv0 = *(const u16x8*)(Wt + (size_t)(arow      ) * K + k0 + akoff);
        bv1 = *(const u16x8*)(Wt + (size_t)(arow +  64) * K + k0 + akoff);
        bv2 = *(const u16x8*)(Wt + (size_t)(arow + 128) * K + k0 + akoff);
    };
    auto swrite = [&]() {
        if (tid < 128) *(u16x8*)&As[arow][akoff] = av;
        *(u16x8*)&Bs[arow][akoff] = bv0;
        *(u16x8*)&Bs[arow + 64][akoff] = bv1;
        *(u16x8*)&Bs[arow + 128][akoff] = bv2;
    };

    gload(0);
    for (int kc = 0; kc < nK; ++kc) {
        __syncthreads();
        swrite();
        __syncthreads();
        if (kc + 1 < nK) gload((kc + 1) << 5);
        bf16x8 af = *(const bf16x8*)&As[mt * 16 + l15][g * 8];
        bf16x8 bfr[6];
#pragma unroll
        for (int nt = 0; nt < 6; ++nt) bfr[nt] = *(const bf16x8*)&Bs[nh * 96 + nt * 16 + l15][g * 8];
#pragma unroll
        for (int nt = 0; nt < 6; ++nt)
            acc[nt] = __builtin_amdgcn_mfma_f32_16x16x32_bf16(af, bfr[nt], acc[nt], 0, 0, 0);
    }

    float ssp[4] = {0.f, 0.f, 0.f, 0.f};
#pragma unroll
    for (int r2 = 0; r2 < 4; ++r2) {
        const int m = m0 + mt * 16 + g * 4 + r2;
#pragma unroll
        for (int nt = 0; nt < 6; ++nt) {
            const int n = nh * 96 + nt * 16 + l15;
            float rres = RESBF16 ? bf2f(((const unsigned short*)Resp)[(size_t)m * E_ + n])
                                 : ((const float*)Resp)[(size_t)m * E_ + n];
            float v = acc[nt][r2] + rres;
            acc[nt][r2] = v;
            ssp[r2] += v * v;
        }
    }
#pragma unroll
    for (int off = 1; off < 16; off <<= 1)
#pragma unroll
        for (int r2 = 0; r2 < 4; ++r2)
            ssp[r2] += __shfl_xor(ssp[r2], off);
    if (l15 == 0) {
#pragma unroll
        for (int r2 = 0; r2 < 4; ++r2)
            ss_red[w][g * 4 + r2] = ssp[r2];
    }
    __syncthreads();
#pragma unroll
    for (int r2 = 0; r2 < 4; ++r2) {
        const int lr = g * 4 + r2;
        const float ss = ss_red[mt][lr] + ss_red[2 + mt][lr];
        const float inv = rsqrtf(ss * (1.0f / 192.0f) + 1.1920929e-07f);
        const int m = m0 + mt * 16 + lr;
        size_t orow;
        if (EPI == 2) {        // X -> XR
            const int b = m >> 13, rr = (m >> 3) & 1023, gg = m & 7;
            orow = (((size_t)b * G_ + gg) << 10) + rr;
        } else if (EPI == 3) { // XR -> X
            const int b = m >> 13, gg = (m >> 10) & 7, rr = m & 1023;
            orow = ((((size_t)b << 10) + rr) << 3) + gg;
        } else {
            orow = m;
        }
#pragma unroll
        for (int nt = 0; nt < 6; ++nt) {
            const int n = nh * 96 + nt * 16 + l15;
            const float v = acc[nt][r2] * inv * gvec[n];
            if (EPI == 4) ((float*)Cp)[orow * E_ + n] = v;
            else          ((unsigned short*)Cp)[orow * E_ + n] = f2bf(v);
        }
    }
}

// ---- Fused feature-attention block (R10 form — measured ~10 us, keep):
// 32 rows (= 4 seqs of G=8) per block. QKV GEMM (N=576) -> QKV in LDS ->
// in-block attn1 -> wo1 GEMM (A from LDS) -> +res -> row-RMS*g1 ->
// transposed (X->XR) bf16 store. Grid M/32 = 1024.
template<bool AF32>
__global__ __launch_bounds__(256)
void k_featblock(const void* __restrict__ Xin, const unsigned short* __restrict__ Wqkv,
                 const unsigned short* __restrict__ Wo, const float* __restrict__ gvec,
                 unsigned short* __restrict__ Ynb)
{
    __shared__ __align__(16) unsigned char raw[576 * 40 * 2];   // B-staging / QKVl union
    __shared__ __align__(16) unsigned short As[32][40];
    __shared__ __align__(16) unsigned short Tl[32][200];
    __shared__ float ss_red[4][32];

    unsigned short (*Bq)[40]    = (unsigned short (*)[40])raw;   // [576][40] (QKV K-loop)
    unsigned short (*QKVl)[584] = (unsigned short (*)[584])raw;  // [32][584] (after)
    unsigned short (*Bo)[40]    = (unsigned short (*)[40])raw;   // [192][40] (wo1 K-loop)

    const int m0 = blockIdx.x * 32;
    const int tid = threadIdx.x;
    const int w = tid >> 6, lane = tid & 63, l15 = lane & 15, g = lane >> 4;
    const int arow = (tid & 127) >> 2, akoff = (tid & 3) << 3;

    // ---- phase 1: QKV = A @ Wqkv^T, acc 32x576 ----
    f32x4 acc[2][9];
#pragma unroll
    for (int mt = 0; mt < 2; ++mt)
#pragma unroll
        for (int nt = 0; nt < 9; ++nt)
#pragma unroll
            for (int r2 = 0; r2 < 4; ++r2) acc[mt][nt][r2] = 0.f;

    for (int kc = 0; kc < 6; ++kc) {
        const int k0 = kc << 5;
        __syncthreads();
        if (tid < 128) {
            u16x8 aw;
            if (AF32) {
                const float* ap = (const float*)Xin + (size_t)(m0 + arow) * E_ + k0 + akoff;
                float4 x = *(const float4*)ap, y = *(const float4*)(ap + 4);
                aw[0] = f2bf(x.x); aw[1] = f2bf(x.y); aw[2] = f2bf(x.z); aw[3] = f2bf(x.w);
                aw[4] = f2bf(y.x); aw[5] = f2bf(y.y); aw[6] = f2bf(y.z); aw[7] = f2bf(y.w);
            } else {
                aw = *(const u16x8*)((const unsigned short*)Xin + (size_t)(m0 + arow) * E_ + k0 + akoff);
            }
            *(u16x8*)&As[arow][akoff] = aw;
        }
#pragma unroll
        for (int j = 0; j < 9; ++j) {
            const int v = tid + 256 * j;
            const int br = v >> 2, bk = (v & 3) << 3;
            *(u16x8*)&Bq[br][bk] = *(const u16x8*)(Wqkv + (size_t)br * E_ + k0 + bk);
        }
        __syncthreads();
        bf16x8 af0 = *(const bf16x8*)&As[l15][g * 8];
        bf16x8 af1 = *(const bf16x8*)&As[16 + l15][g * 8];
#pragma unroll
        for (int nt = 0; nt < 9; ++nt) {
            bf16x8 bf = *(const bf16x8*)&Bq[w * 144 + nt * 16 + l15][g * 8];
            acc[0][nt] = __builtin_amdgcn_mfma_f32_16x16x32_bf16(af0, bf, acc[0][nt], 0, 0, 0);
            acc[1][nt] = __builtin_amdgcn_mfma_f32_16x16x32_bf16(af1, bf, acc[1][nt], 0, 0, 0);
        }
    }
    __syncthreads();
    // spill QKV to LDS (overlays B-staging; barrier above protects)
#pragma unroll
    for (int mt = 0; mt < 2; ++mt)
#pragma unroll
        for (int r2 = 0; r2 < 4; ++r2)
#pragma unroll
            for (int nt = 0; nt < 9; ++nt)
                QKVl[mt * 16 + g * 4 + r2][w * 144 + nt * 16 + l15] = f2bf(acc[mt][nt][r2]);
    __syncthreads();

    // ---- phase 2: attn1 (wave w = seq w; lane = i*8+j over G=8) ----
    {
        const int i = lane >> 3, j = lane & 7;
        const int r0 = w * 8;
#pragma unroll
        for (int h = 0; h < 6; ++h) {
            float s = 0.f;
#pragma unroll
            for (int d8 = 0; d8 < 4; ++d8) {
                u16x8 qv = *(const u16x8*)&QKVl[r0 + i][h * 32 + d8 * 8];
                u16x8 kv = *(const u16x8*)&QKVl[r0 + j][192 + h * 32 + d8 * 8];
#pragma unroll
                for (int e = 0; e < 8; ++e) s += bf2f(qv[e]) * bf2f(kv[e]);
            }
            float mx = s;
#pragma unroll
            for (int off = 1; off < 8; off <<= 1) mx = fmaxf(mx, __shfl_xor(mx, off));
            float p = __expf(s - mx);
            float sum = p;
#pragma unroll
            for (int off = 1; off < 8; off <<= 1) sum += __shfl_xor(sum, off);
            p /= sum;
            const int base = lane & ~7;
            float o0 = 0.f, o1 = 0.f, o2 = 0.f, o3 = 0.f;
#pragma unroll
            for (int jj = 0; jj < 8; ++jj) {
                float pj = __shfl(p, base + jj);
                ushort4 vv = *(const ushort4*)&QKVl[r0 + jj][384 + h * 32 + j * 4];
                o0 += pj * bf2f(vv.x); o1 += pj * bf2f(vv.y);
                o2 += pj * bf2f(vv.z); o3 += pj * bf2f(vv.w);
            }
            ushort4 ov; ov.x = f2bf(o0); ov.y = f2bf(o1); ov.z = f2bf(o2); ov.w = f2bf(o3);
            *(ushort4*)&Tl[r0 + i][h * 32 + j * 4] = ov;
        }
    }
    __syncthreads();

    // ---- phase 3: T @ wo1^T (A from LDS), wave owns 48 cols ----
    f32x4 acc2[2][3];
#pragma unroll
    for (int mt = 0; mt < 2; ++mt)
#pragma unroll
        for (int nt = 0; nt < 3; ++nt)
#pragma unroll
            for (int r2 = 0; r2 < 4; ++r2) acc2[mt][nt][r2] = 0.f;

    for (int kc = 0; kc < 6; ++kc) {
        const int k0 = kc << 5;
        __syncthreads();
#pragma unroll
        for (int j = 0; j < 3; ++j) {
            const int v = tid + 256 * j;
            const int br = v >> 2, bk = (v & 3) << 3;
            *(u16x8*)&Bo[br][bk] = *(const u16x8*)(Wo + (size_t)br * E_ + k0 + bk);
        }
        __syncthreads();
        bf16x8 af0 = *(const bf16x8*)&Tl[l15][k0 + g * 8];
        bf16x8 af1 = *(const bf16x8*)&Tl[16 + l15][k0 + g * 8];
#pragma unroll
        for (int nt = 0; nt < 3; ++nt) {
            bf16x8 bf = *(const bf16x8*)&Bo[w * 48 + nt * 16 + l15][g * 8];
            acc2[0][nt] = __builtin_amdgcn_mfma_f32_16x16x32_bf16(af0, bf, acc2[0][nt], 0, 0, 0);
            acc2[1][nt] = __builtin_amdgcn_mfma_f32_16x16x32_bf16(af1, bf, acc2[1][nt], 0, 0, 0);
        }
    }
    __syncthreads();

    // ---- epilogue: +res, row-RMS*g1, transpose X->XR, bf16 store ----
    float ssp[2][4] = {};
#pragma unroll
    for (int mt = 0; mt < 2; ++mt)
#pragma unroll
        for (int r2 = 0; r2 < 4; ++r2) {
            const int m = m0 + mt * 16 + g * 4 + r2;
#pragma unroll
            for (int nt = 0; nt < 3; ++nt) {
                const int n = w * 48 + nt * 16 + l15;
                float rres = AF32 ? ((const float*)Xin)[(size_t)m * E_ + n]
                                  : bf2f(((const unsigned short*)Xin)[(size_t)m * E_ + n]);
                float v = acc2[mt][nt][r2] + rres;
                acc2[mt][nt][r2] = v;
                ssp[mt][r2] += v * v;
            }
        }
#pragma unroll
    for (int off = 1; off < 16; off <<= 1)
#pragma unroll
        for (int mt = 0; mt < 2; ++mt)
#pragma unroll
            for (int r2 = 0; r2 < 4; ++r2)
                ssp[mt][r2] += __shfl_xor(ssp[mt][r2], off);
    if (l15 == 0) {
#pragma unroll
        for (int mt = 0; mt < 2; ++mt)
#pragma unroll
            for (int r2 = 0; r2 < 4; ++r2)
                ss_red[w][mt * 16 + g * 4 + r2] = ssp[mt][r2];
    }
    __syncthreads();
#pragma unroll
    for (int mt = 0; mt < 2; ++mt)
#pragma unroll
        for (int r2 = 0; r2 < 4; ++r2) {
            const int row = mt * 16 + g * 4 + r2;
            const float ss = ss_red[0][row] + ss_red[1][row] + ss_red[2][row] + ss_red[3][row];
            const float inv = rsqrtf(ss * (1.0f / 192.0f) + 1.1920929e-07f);
            const int m = m0 + row;
            const int b = m >> 13, rr = (m >> 3) & 1023, gg = m & 7;
            const size_t orow = (((size_t)(b * G_ + gg)) << 10) + rr;
#pragma unroll
            for (int nt = 0; nt < 3; ++nt) {
                const int n = w * 48 + nt * 16 + l15;
                Ynb[orow * E_ + n] = f2bf(acc2[mt][nt][r2] * inv * gvec[n]);
            }
        }
}

// ---- Row attention (R8 form — local optimum): MFMA flash, exp2 domain,
// register-resident P, V via tr-subtile + ds_read_b64_tr_b16, ones-row
// denominator, defer-max, 64-q blocks, reg prefetch.
__global__ __launch_bounds__(256)
void k_attn2(const unsigned short* __restrict__ QKV, unsigned short* __restrict__ T,
             const int* __restrict__ sep_ptr)
{
    __shared__ __align__(16) unsigned short K_lds[64][40];
    __shared__ __align__(16) unsigned short V_lds[2048];   // [dg(2)][kblk(16)][4][16]

    const int sep = *sep_ptr;
    const int bid = blockIdx.x;
    const int sh = ((bid >> 7) << 3) | (bid & 7);   // same (s,h) => same XCD
    const int qtile = (bid >> 3) & 15;
    const int s = sh / H_, h = sh % H_;
    const int q0 = qtile * 64;

    const int tid = threadIdx.x;
    const int w = tid >> 6;
    const int lane = tid & 63;
    const int l15 = lane & 15;
    const int g = lane >> 4;

    const int qrow = q0 + w * 16 + l15;
    u16x8 qf = *(const u16x8*)(QKV + ((size_t)s * R_ + qrow) * 576 + h * D_ + g * 8);

    u16x8 onesu;
#pragma unroll
    for (int e = 0; e < 8; ++e) onesu[e] = 0x3F80;  // bf16 1.0
    const bf16x8 onesf = (bf16x8)onesu;

    const bool lo = (q0 < sep);
    const bool hi = (q0 + 64 > sep);
    const int npass = (lo && hi) ? 2 : 1;
    const int nChunk = (sep + 63) >> 6;

    const int skey = tid >> 2;
    const int sg   = tid & 3;
    const int vst = ((sg >> 1) * 16 + (skey >> 2)) * 64 + (skey & 3) * 16 + (sg & 1) * 8;
    const unsigned vaddr = (unsigned)(size_t)&V_lds[0] + (unsigned)(g * 128 + l15 * 2);

    for (int pass = 0; pass < npass; ++pass) {
        const int hk = (pass == 0) ? (lo ? h : 0) : 0;
        const unsigned short* Kb = QKV + (size_t)s * R_ * 576 + 192 + hk * D_;
        const unsigned short* Vb = QKV + (size_t)s * R_ * 576 + 384 + hk * D_;

        float mrun = -1e30f;
        f32x4 o0 = {0.f, 0.f, 0.f, 0.f};
        f32x4 o1 = {0.f, 0.f, 0.f, 0.f};
        f32x4 o2 = {0.f, 0.f, 0.f, 0.f};   // ones-row: running sum of P

        u16x8 kv_k = *(const u16x8*)(Kb + (size_t)skey * 576 + sg * 8);
        u16x8 kv_v = *(const u16x8*)(Vb + (size_t)skey * 576 + sg * 8);

        for (int kc = 0; kc < nChunk; ++kc) {
            const int kbase = kc * 64;
            const bool full = (kbase + 64 <= sep);
            __syncthreads();
            *(u16x8*)&K_lds[skey][sg * 8] = kv_k;
            *(u16x8*)&V_lds[vst] = kv_v;
            __syncthreads();
            if (kc + 1 < nChunk) {
                kv_k = *(const u16x8*)(Kb + (size_t)(kbase + 64 + skey) * 576 + sg * 8);
                kv_v = *(const u16x8*)(Vb + (size_t)(kbase + 64 + skey) * 576 + sg * 8);
            }

            f32x4 sc[4];
            const f32x4 zf = {0.f, 0.f, 0.f, 0.f};
            __builtin_amdgcn_s_setprio(1);
#pragma unroll
            for (int t = 0; t < 4; ++t) {
                bf16x8 a = *(const bf16x8*)&K_lds[t * 16 + l15][g * 8];
                sc[t] = __builtin_amdgcn_mfma_f32_16x16x32_bf16(a, (bf16x8)qf, zf, 0, 0, 0);
            }
            __builtin_amdgcn_s_setprio(0);
            if (!full) {
#pragma unroll
                for (int t = 0; t < 4; ++t)
#pragma unroll
                    for (int r = 0; r < 4; ++r)
                        if (kbase + t * 16 + g * 4 + r >= sep) sc[t][r] = -1e30f;
            }
            float mx = fmaxf(fmaxf(sc[0][0], sc[0][1]), sc[0][2]);
            mx = fmaxf(fmaxf(sc[0][3], sc[1][0]), mx);
            mx = fmaxf(fmaxf(sc[1][1], sc[1][2]), mx);
            mx = fmaxf(fmaxf(sc[1][3], sc[2][0]), mx);
            mx = fmaxf(fmaxf(sc[2][1], sc[2][2]), mx);
            mx = fmaxf(fmaxf(sc[2][3], sc[3][0]), mx);
            mx = fmaxf(fmaxf(sc[3][1], sc[3][2]), mx);
            mx = fmaxf(mx, sc[3][3]);
            if (!__all((int)(mx <= mrun + 11.0f))) {
                mx = fmaxf(mx, __shfl_xor(mx, 16));
                mx = fmaxf(mx, __shfl_xor(mx, 32));
                const float mnew = fmaxf(mrun, mx);
                const float scl = exp2f(mrun - mnew);
#pragma unroll
                for (int r = 0; r < 4; ++r) { o0[r] *= scl; o1[r] *= scl; o2[r] *= scl; }
                mrun = mnew;
            }
            bf16x8 pb0, pb1;
            {
                u16x8 p0, p1;
#pragma unroll
                for (int r = 0; r < 4; ++r) {
                    p0[r]     = f2bf(exp2f(sc[0][r] - mrun));
                    p0[4 + r] = f2bf(exp2f(sc[1][r] - mrun));
                    p1[r]     = f2bf(exp2f(sc[2][r] - mrun));
                    p1[4 + r] = f2bf(exp2f(sc[3][r] - mrun));
                }
                pb0 = (bf16x8)p0; pb1 = (bf16x8)p1;
            }
            unsigned long long t0, t1, t2, t3, t4, t5, t6, t7;
            asm volatile(
                "ds_read_b64_tr_b16 %0, %8 offset:0\n\t"
                "ds_read_b64_tr_b16 %1, %8 offset:512\n\t"
                "ds_read_b64_tr_b16 %2, %8 offset:1024\n\t"
                "ds_read_b64_tr_b16 %3, %8 offset:1536\n\t"
                "ds_read_b64_tr_b16 %4, %8 offset:2048\n\t"
                "ds_read_b64_tr_b16 %5, %8 offset:2560\n\t"
                "ds_read_b64_tr_b16 %6, %8 offset:3072\n\t"
                "ds_read_b64_tr_b16 %7, %8 offset:3584\n\t"
                "s_waitcnt lgkmcnt(0)"
                : "=&v"(t0), "=&v"(t1), "=&v"(t2), "=&v"(t3),
                  "=&v"(t4), "=&v"(t5), "=&v"(t6), "=&v"(t7)
                : "v"(vaddr)
                : "memory");
            __builtin_amdgcn_sched_barrier(0);
            __builtin_amdgcn_s_setprio(1);
            o0 = __builtin_amdgcn_mfma_f32_16x16x32_bf16(mk8(t0, t1), pb0, o0, 0, 0, 0);
            o1 = __builtin_amdgcn_mfma_f32_16x16x32_bf16(mk8(t4, t5), pb0, o1, 0, 0, 0);
            o2 = __builtin_amdgcn_mfma_f32_16x16x32_bf16(onesf,       pb0, o2, 0, 0, 0);
            o0 = __builtin_amdgcn_mfma_f32_16x16x32_bf16(mk8(t2, t3), pb1, o0, 0, 0, 0);
            o1 = __builtin_amdgcn_mfma_f32_16x16x32_bf16(mk8(t6, t7), pb1, o1, 0, 0, 0);
            o2 = __builtin_amdgcn_mfma_f32_16x16x32_bf16(onesf,       pb1, o2, 0, 0, 0);
            __builtin_amdgcn_s_setprio(0);
        }

        const bool valid = (npass == 1) || (pass == 0 ? (qrow < sep) : (qrow >= sep));
        if (valid) {
            const float inv = 1.f / o2[0];
            unsigned short* tp = T + ((size_t)s * R_ + qrow) * E_ + h * D_;
            ushort4 v0, v1;
            v0.x = f2bf(o0[0] * inv); v0.y = f2bf(o0[1] * inv);
            v0.z = f2bf(o0[2] * inv); v0.w = f2bf(o0[3] * inv);
            v1.x = f2bf(o1[0] * inv); v1.y = f2bf(o1[1] * inv);
            v1.z = f2bf(o1[2] * inv); v1.w = f2bf(o1[3] * inv);
            *(ushort4*)(tp + g * 4)      = v0;
            *(ushort4*)(tp + 16 + g * 4) = v1;
        }
    }
}

extern "C" void kernel_launch(void* const* d_in, const int* in_sizes, int n_in,
                              void* d_out, int out_size, void* d_ws, size_t ws_size,
                              hipStream_t stream) {
    const float* hidden = (const float*)d_in[0];
    const float* Wq1 = (const float*)d_in[1];
    const float* Wk1 = (const float*)d_in[2];
    const float* Wv1 = (const float*)d_in[3];
    const float* Wo1 = (const float*)d_in[4];
    const float* Wq2 = (const float*)d_in[5];
    const float* Wk2 = (const float*)d_in[6];
    const float* Wv2 = (const float*)d_in[7];
    const float* Wo2 = (const float*)d_in[8];
    const float* W1  = (const float*)d_in[9];
    const float* W2  = (const float*)d_in[10];
    const float* g1  = (const float*)d_in[11];
    const float* g2  = (const float*)d_in[12];
    const float* g3  = (const float*)d_in[13];
    const int*   sep = (const int*)d_in[14];

    float* Xout = (float*)d_out;                    // final f32 X-layout output
    unsigned short* ws = (unsigned short*)d_ws;
    unsigned short* QKVb = ws;                      // [M][576] bf16 (aliases H1 [M][384])
    unsigned short* Tb   = QKVb + (size_t)M_ * 576;
    unsigned short* Ynb  = Tb + NBUF;               // rms-g1 output, XR layout
    unsigned short* Xcb  = Ynb + NBUF;              // rms-g2 output, X layout
    unsigned short* Xb   = Xcb + NBUF;              // inter-layer residual (layers 0-2)
    unsigned short* Wt   = Xb + NBUF;
    unsigned short* H1b  = QKVb;

    const dim3 blk(256);
    const dim3 gQKV(M_ / 64, 3);
    const dim3 gW1(M_ / 64, 2);
    const dim3 g32(M_ / 32);                        // 1024 blocks
    const dim3 gA2(32 * H_ * 16);

    k_convw_all<<<dim3(432 * L_), blk, 0, stream>>>(Wq1, Wk1, Wv1, Wo1, Wq2, Wk2, Wv2, Wo2, W1, W2, Wt);

    for (int i = 0; i < L_; ++i) {
        unsigned short* wl = Wt + (size_t)i * WPL;
        const unsigned short* wqkv1 = wl;
        const unsigned short* wo1   = wl + 3 * (size_t)E_ * E_;
        const unsigned short* wqkv2 = wl + 4 * (size_t)E_ * E_;
        const unsigned short* wo2   = wl + 7 * (size_t)E_ * E_;
        const unsigned short* w1    = wl + 8 * (size_t)E_ * E_;
        const unsigned short* w2    = wl + 8 * (size_t)E_ * E_ + (size_t)E_ * F_;
        const float* g1i = g1 + (size_t)i * E_;
        const float* g2i = g2 + (size_t)i * E_;
        const float* g3i = g3 + (size_t)i * E_;

        // --- fused feature-attention block: X/hidden -> Ynb (XR) ---
        if (i == 0)
            k_featblock<true><<<g32, blk, 0, stream>>>(hidden, wqkv1, wo1, g1i, Ynb);
        else
            k_featblock<false><<<g32, blk, 0, stream>>>(Xb, wqkv1, wo1, g1i, Ynb);
        // --- row attention block ---
        k_gemm_mfma<true, 0><<<gQKV, blk, 0, stream>>>(Ynb, wqkv2, QKVb, 576, E_);
        k_attn2<<<gA2, blk, 0, stream>>>(QKVb, Tb, sep);
        k_gemm_rms32<true, 3><<<g32, blk, 0, stream>>>(Tb, wo2, Ynb, g2i, Xcb, E_);
        // --- MLP block ---
        k_gemm_mfma<true, 1><<<gW1, blk, 0, stream>>>(Xcb, w1, H1b, F_, E_);
        if (i == L_ - 1)
            k_gemm_rms32<true, 4><<<g32, blk, 0, stream>>>(H1b, w2, Xcb, g3i, Xout, F_);
        else
            k_gemm_rms32<true, 5><<<g32, blk, 0, stream>>>(H1b, w2, Xcb, g3i, Xb, F_);
    }
}